// Round 1
// baseline (3439.349 us; speedup 1.0000x reference)
//
#include <hip/hip_runtime.h>

#define NU 100000
#define NM 20000
#define DD 64
#define RR 5
#define EE 400000

typedef __attribute__((ext_vector_type(8))) short bf16x8;
typedef __attribute__((ext_vector_type(4))) float f32x4;

static __device__ __forceinline__ short f2bf(float f) {
  unsigned u = __builtin_bit_cast(unsigned, f);
  u += 0x7fffu + ((u >> 16) & 1u);   // RTNE (inputs have no NaN)
  return (short)(u >> 16);
}

static __device__ __forceinline__ bf16x8 cvt8(const float* __restrict__ p) {
  const float4 a = *(const float4*)p;
  const float4 b = *(const float4*)(p + 4);
  bf16x8 o;
  o[0] = f2bf(a.x); o[1] = f2bf(a.y); o[2] = f2bf(a.z); o[3] = f2bf(a.w);
  o[4] = f2bf(b.x); o[5] = f2bf(b.y); o[6] = f2bf(b.z); o[7] = f2bf(b.w);
  return o;
}

static __device__ __forceinline__ float sigm(float x) { return 1.f / (1.f + __expf(-x)); }
static __device__ __forceinline__ float gelu(float x) {
  return 0.5f * x * (1.f + erff(x * 0.70710678118654752f));
}

// ---------------------------------------------------------------------------
// Main fused kernel: per relation r, per 16-edge tile:
//   rf_u = rfeat @ rw_u.T ; rf_m = rfeat @ rw_m.T ; dots vs rs_u/ps_u/rs_m/ps_m
// all via one MFMA pass (B = [rw_u.T | rw_m.T | rs_u ps_u rs_m ps_m | 0-pad]),
// then gather h rows + cj, combine, atomic-scatter into agg buffers.
// Column permutation: tile t, col c -> output dim d = 4*c + t  (lane-contiguous d).
// ---------------------------------------------------------------------------
__global__ __launch_bounds__(256) void gcmc_main(
    const int* __restrict__ edges_u, const int* __restrict__ edges_m,
    const float* __restrict__ rfeat,
    const float* __restrict__ W_user, const float* __restrict__ W_movie,
    const float* __restrict__ ps_u, const float* __restrict__ rs_u, const float* __restrict__ rw_u,
    const float* __restrict__ ps_m, const float* __restrict__ rs_m, const float* __restrict__ rw_m,
    const float* __restrict__ user_cj, const float* __restrict__ movie_cj,
    float* __restrict__ user_agg, float* __restrict__ movie_agg)
{
  const int r    = blockIdx.y;
  const int lane = threadIdx.x & 63;
  const int wid  = threadIdx.x >> 6;
  const int c    = lane & 15;   // col-within-tile
  const int kr   = lane >> 4;   // k-group 0..3
  const int wtile = blockIdx.x * 4 + wid;

  // ---- B fragments in registers (bf16), loaded once per wave ----
  bf16x8 Bu[4][2], Bm[4][2], Bs[2];
#pragma unroll
  for (int t = 0; t < 4; ++t) {
#pragma unroll
    for (int s = 0; s < 2; ++s) {
      Bu[t][s] = cvt8(rw_u + ((size_t)r * DD + (4 * c + t)) * DD + s * 32 + kr * 8);
      Bm[t][s] = cvt8(rw_m + ((size_t)r * DD + (4 * c + t)) * DD + s * 32 + kr * 8);
    }
  }
#pragma unroll
  for (int s = 0; s < 2; ++s) {
    if (c < 4) {
      const float* v = (c == 0 ? rs_u : c == 1 ? ps_u : c == 2 ? rs_m : ps_m)
                       + r * DD + s * 32 + kr * 8;
      Bs[s] = cvt8(v);
    } else {
      bf16x8 z = {0, 0, 0, 0, 0, 0, 0, 0};
      Bs[s] = z;
    }
  }

  for (int tt = 0; tt < 8; ++tt) {
    const int tile = wtile * 8 + tt;
    if (tile >= (EE / 16)) break;
    const int e0 = tile * 16;

    // ---- A fragments: rows = 16 edges, K = 64 feature dims ----
    const float* arow = rfeat + ((size_t)r * EE + e0 + c) * DD + kr * 8;
    const bf16x8 A0 = cvt8(arow);        // k in [0,32)
    const bf16x8 A1 = cvt8(arow + 32);   // k in [32,64)

    f32x4 z4 = {0.f, 0.f, 0.f, 0.f};
    f32x4 Cu[4], Cm[4], Cs;
#pragma unroll
    for (int t = 0; t < 4; ++t) { Cu[t] = z4; Cm[t] = z4; }
    Cs = z4;

#pragma unroll
    for (int t = 0; t < 4; ++t) {
      Cu[t] = __builtin_amdgcn_mfma_f32_16x16x32_bf16(A0, Bu[t][0], Cu[t], 0, 0, 0);
      Cu[t] = __builtin_amdgcn_mfma_f32_16x16x32_bf16(A1, Bu[t][1], Cu[t], 0, 0, 0);
      Cm[t] = __builtin_amdgcn_mfma_f32_16x16x32_bf16(A0, Bm[t][0], Cm[t], 0, 0, 0);
      Cm[t] = __builtin_amdgcn_mfma_f32_16x16x32_bf16(A1, Bm[t][1], Cm[t], 0, 0, 0);
    }
    Cs = __builtin_amdgcn_mfma_f32_16x16x32_bf16(A0, Bs[0], Cs, 0, 0, 0);
    Cs = __builtin_amdgcn_mfma_f32_16x16x32_bf16(A1, Bs[1], Cs, 0, 0, 0);

    // ---- Epilogue: per edge-row, gather + combine + atomic scatter ----
    const int ebase = r * EE + e0;
#pragma unroll
    for (int q = 0; q < 4; ++q) {
      const int rr = kr * 4 + q;          // this lane's edge row
      const int e  = ebase + rr;
      const int src = (lane & 48);        // lane group holding cols 0..3 of Cs
      const float su = __shfl(Cs[q], src);
      const float pu = __shfl(Cs[q], src | 1);
      const float sm = __shfl(Cs[q], src | 2);
      const float pm = __shfl(Cs[q], src | 3);
      const float sgu = sigm(su), pau = sigm(pu);
      const float sgm_ = sigm(sm), pam = sigm(pm);

      const int eu = edges_u[e];
      const int em = edges_m[e];
      const float cju = user_cj[eu];
      const float cjm = movie_cj[em];

      const float4 hu = *(const float4*)(W_user + ((size_t)r * NU + eu) * DD + 4 * c);
      const float4 hm = *(const float4*)(W_movie + ((size_t)r * NM + em) * DD + 4 * c);

      float* mdst = movie_agg + (size_t)em * DD + 4 * c;
      float* udst = user_agg + (size_t)eu * DD + 4 * c;

      atomicAdd(mdst + 0, (hu.x * pau + Cu[0][q] * sgu) * cju);
      atomicAdd(mdst + 1, (hu.y * pau + Cu[1][q] * sgu) * cju);
      atomicAdd(mdst + 2, (hu.z * pau + Cu[2][q] * sgu) * cju);
      atomicAdd(mdst + 3, (hu.w * pau + Cu[3][q] * sgu) * cju);

      atomicAdd(udst + 0, (hm.x * pam + Cm[0][q] * sgm_) * cjm);
      atomicAdd(udst + 1, (hm.y * pam + Cm[1][q] * sgm_) * cjm);
      atomicAdd(udst + 2, (hm.z * pam + Cm[2][q] * sgm_) * cjm);
      atomicAdd(udst + 3, (hm.w * pam + Cm[3][q] * sgm_) * cjm);
    }
  }
}

// ---------------------------------------------------------------------------
// FC kernel (in-place on d_out): row -> gelu(row*ci) @ W.T + b, 16 rows/wave.
// ---------------------------------------------------------------------------
__global__ __launch_bounds__(256) void gcmc_fc(
    float* __restrict__ out,
    const float* __restrict__ user_ci, const float* __restrict__ movie_ci,
    const float* __restrict__ ufc_w, const float* __restrict__ ufc_b,
    const float* __restrict__ ifc_w, const float* __restrict__ ifc_b)
{
  const int wt   = blockIdx.x * 4 + (threadIdx.x >> 6);
  const int lane = threadIdx.x & 63;
  const int c    = lane & 15;
  const int kr   = lane >> 4;
  const bool isU = wt < (NU / 16);
  float* base        = isU ? out : out + (size_t)NU * DD;
  const float* ci    = isU ? user_ci : movie_ci;
  const float* W     = isU ? ufc_w : ifc_w;
  const float* bias  = isU ? ufc_b : ifc_b;
  const int row0 = (isU ? wt : wt - (NU / 16)) * 16;

  // B: tile t, col c -> output dim d = 4c+t ; B[k][.] = W[d][k]
  bf16x8 B[4][2];
#pragma unroll
  for (int t = 0; t < 4; ++t)
#pragma unroll
    for (int s = 0; s < 2; ++s)
      B[t][s] = cvt8(W + (size_t)(4 * c + t) * DD + s * 32 + kr * 8);

  const float civ = ci[row0 + c];
  const float* arow = base + (size_t)(row0 + c) * DD + kr * 8;

  bf16x8 A0, A1;
  {
    const float4 a = *(const float4*)arow;
    const float4 b = *(const float4*)(arow + 4);
    const float4 a2 = *(const float4*)(arow + 32);
    const float4 b2 = *(const float4*)(arow + 36);
    A0[0] = f2bf(gelu(a.x * civ));  A0[1] = f2bf(gelu(a.y * civ));
    A0[2] = f2bf(gelu(a.z * civ));  A0[3] = f2bf(gelu(a.w * civ));
    A0[4] = f2bf(gelu(b.x * civ));  A0[5] = f2bf(gelu(b.y * civ));
    A0[6] = f2bf(gelu(b.z * civ));  A0[7] = f2bf(gelu(b.w * civ));
    A1[0] = f2bf(gelu(a2.x * civ)); A1[1] = f2bf(gelu(a2.y * civ));
    A1[2] = f2bf(gelu(a2.z * civ)); A1[3] = f2bf(gelu(a2.w * civ));
    A1[4] = f2bf(gelu(b2.x * civ)); A1[5] = f2bf(gelu(b2.y * civ));
    A1[6] = f2bf(gelu(b2.z * civ)); A1[7] = f2bf(gelu(b2.w * civ));
  }

  f32x4 z4 = {0.f, 0.f, 0.f, 0.f};
  f32x4 C[4];
#pragma unroll
  for (int t = 0; t < 4; ++t) {
    C[t] = z4;
    C[t] = __builtin_amdgcn_mfma_f32_16x16x32_bf16(A0, B[t][0], C[t], 0, 0, 0);
    C[t] = __builtin_amdgcn_mfma_f32_16x16x32_bf16(A1, B[t][1], C[t], 0, 0, 0);
  }

  const float4 b4 = *(const float4*)(bias + 4 * c);
#pragma unroll
  for (int q = 0; q < 4; ++q) {
    const int row = row0 + kr * 4 + q;
    float4 o;
    o.x = C[0][q] + b4.x; o.y = C[1][q] + b4.y;
    o.z = C[2][q] + b4.z; o.w = C[3][q] + b4.w;
    *(float4*)(base + (size_t)row * DD + 4 * c) = o;
  }
}

extern "C" void kernel_launch(void* const* d_in, const int* in_sizes, int n_in,
                              void* d_out, int out_size, void* d_ws, size_t ws_size,
                              hipStream_t stream) {
  const int*   edges_u  = (const int*)  d_in[0];
  const int*   edges_m  = (const int*)  d_in[1];
  const float* rfeat    = (const float*)d_in[2];
  const float* W_user   = (const float*)d_in[3];
  const float* W_movie  = (const float*)d_in[4];
  const float* ps_u     = (const float*)d_in[5];
  const float* rs_u     = (const float*)d_in[6];
  const float* rw_u     = (const float*)d_in[7];
  const float* ps_m     = (const float*)d_in[8];
  const float* rs_m     = (const float*)d_in[9];
  const float* rw_m     = (const float*)d_in[10];
  const float* user_cj  = (const float*)d_in[11];
  const float* user_ci  = (const float*)d_in[12];
  const float* movie_cj = (const float*)d_in[13];
  const float* movie_ci = (const float*)d_in[14];
  const float* ufc_w    = (const float*)d_in[15];
  const float* ufc_b    = (const float*)d_in[16];
  const float* ifc_w    = (const float*)d_in[17];
  const float* ifc_b    = (const float*)d_in[18];

  float* out = (float*)d_out;
  // d_out doubles as the aggregation buffer: [user_agg | movie_agg]
  hipMemsetAsync(out, 0, (size_t)out_size * sizeof(float), stream);
  float* user_agg  = out;
  float* movie_agg = out + (size_t)NU * DD;

  // main: 25000 tiles/relation, 8 tiles/wave, 4 waves/block -> 782 blocks x 5 relations
  dim3 g1((EE / 16 + 31) / 32, RR);
  gcmc_main<<<g1, 256, 0, stream>>>(edges_u, edges_m, rfeat, W_user, W_movie,
                                    ps_u, rs_u, rw_u, ps_m, rs_m, rw_m,
                                    user_cj, movie_cj, user_agg, movie_agg);

  // fc: (100000+20000)/16 = 7500 tiles, 4 waves/block -> 1875 blocks
  gcmc_fc<<<7500 / 4, 256, 0, stream>>>(out, user_ci, movie_ci,
                                        ufc_w, ufc_b, ifc_w, ifc_b);
}

// Round 2
// 1140.722 us; speedup vs baseline: 3.0151x; 3.0151x over previous
//
#include <hip/hip_runtime.h>

#define NU 100000
#define NM 20000
#define DD 64
#define RR 5
#define EE 400000
#define NE (RR * EE)            // 2,000,000 total edges
#define NNODE (NM + NU)         // 120,000 combined destination count

typedef __attribute__((ext_vector_type(8))) short bf16x8;
typedef __attribute__((ext_vector_type(4))) float f32x4;

static __device__ __forceinline__ short f2bf(float f) {
  unsigned u = __builtin_bit_cast(unsigned, f);
  u += 0x7fffu + ((u >> 16) & 1u);   // RTNE (inputs have no NaN)
  return (short)(u >> 16);
}
static __device__ __forceinline__ float bf2f(short s) {
  return __builtin_bit_cast(float, ((unsigned)(unsigned short)s) << 16);
}

static __device__ __forceinline__ bf16x8 cvt8(const float* __restrict__ p) {
  const float4 a = *(const float4*)p;
  const float4 b = *(const float4*)(p + 4);
  bf16x8 o;
  o[0] = f2bf(a.x); o[1] = f2bf(a.y); o[2] = f2bf(a.z); o[3] = f2bf(a.w);
  o[4] = f2bf(b.x); o[5] = f2bf(b.y); o[6] = f2bf(b.z); o[7] = f2bf(b.w);
  return o;
}

static __device__ __forceinline__ float sigm(float x) { return 1.f / (1.f + __expf(-x)); }
static __device__ __forceinline__ float gelu(float x) {
  return 0.5f * x * (1.f + erff(x * 0.70710678118654752f));
}

// ---------------------------------------------------------------------------
// Sort machinery: histogram -> scan -> rank-assign
// ---------------------------------------------------------------------------
__global__ __launch_bounds__(256) void hist_k(const int* __restrict__ eu,
                                              const int* __restrict__ em,
                                              int* __restrict__ cnt) {
  const int i = blockIdx.x * 256 + threadIdx.x;
  if (i < NE) {
    atomicAdd(&cnt[em[i]], 1);
    atomicAdd(&cnt[NM + eu[i]], 1);
  }
}

__global__ __launch_bounds__(1024) void scan_k(const int* __restrict__ cnt,
                                               int* __restrict__ off) {
  __shared__ int sums[1024];
  const int t = threadIdx.x;
  const int n = NNODE;
  const int ch = (n + 1023) >> 10;     // 118
  const int b0 = t * ch;
  int s = 0;
  for (int i = 0; i < ch; ++i) { int idx = b0 + i; if (idx < n) s += cnt[idx]; }
  sums[t] = s;
  __syncthreads();
  for (int d = 1; d < 1024; d <<= 1) {
    int x = (t >= d) ? sums[t - d] : 0;
    __syncthreads();
    sums[t] += x;
    __syncthreads();
  }
  int run = (t > 0) ? sums[t - 1] : 0;
  for (int i = 0; i < ch; ++i) {
    int idx = b0 + i;
    if (idx < n) { off[idx] = run; run += cnt[idx]; }
  }
  if (t == 1023) off[n] = sums[1023];
}

__global__ __launch_bounds__(256) void rank_k(const int* __restrict__ eu,
                                              const int* __restrict__ em,
                                              int* __restrict__ cur,
                                              int* __restrict__ slot_m,
                                              int* __restrict__ slot_u) {
  const int i = blockIdx.x * 256 + threadIdx.x;
  if (i < NE) {
    slot_m[i] = atomicAdd(&cur[em[i]], 1);
    slot_u[i] = atomicAdd(&cur[NM + eu[i]], 1) - NE;
  }
}

// ---------------------------------------------------------------------------
// Main fused MFMA kernel (sorted variant): per 16-edge tile compute both
// directions' messages and STORE them (bf16) at their destination-sorted slots.
// Column permutation: tile t, col c -> output dim d = 4*c + t.
// ---------------------------------------------------------------------------
__global__ __launch_bounds__(256) void gcmc_main_sorted(
    const int* __restrict__ edges_u, const int* __restrict__ edges_m,
    const float* __restrict__ rfeat,
    const float* __restrict__ W_user, const float* __restrict__ W_movie,
    const float* __restrict__ ps_u, const float* __restrict__ rs_u, const float* __restrict__ rw_u,
    const float* __restrict__ ps_m, const float* __restrict__ rs_m, const float* __restrict__ rw_m,
    const float* __restrict__ user_cj, const float* __restrict__ movie_cj,
    const int* __restrict__ slot_m, const int* __restrict__ slot_u,
    short* __restrict__ msg_m, short* __restrict__ msg_u)
{
  const int r    = blockIdx.y;
  const int lane = threadIdx.x & 63;
  const int wid  = threadIdx.x >> 6;
  const int c    = lane & 15;
  const int kr   = lane >> 4;
  const int wtile = blockIdx.x * 4 + wid;

  bf16x8 Bu[4][2], Bm[4][2], Bs[2];
#pragma unroll
  for (int t = 0; t < 4; ++t) {
#pragma unroll
    for (int s = 0; s < 2; ++s) {
      Bu[t][s] = cvt8(rw_u + ((size_t)r * DD + (4 * c + t)) * DD + s * 32 + kr * 8);
      Bm[t][s] = cvt8(rw_m + ((size_t)r * DD + (4 * c + t)) * DD + s * 32 + kr * 8);
    }
  }
#pragma unroll
  for (int s = 0; s < 2; ++s) {
    if (c < 4) {
      const float* v = (c == 0 ? rs_u : c == 1 ? ps_u : c == 2 ? rs_m : ps_m)
                       + r * DD + s * 32 + kr * 8;
      Bs[s] = cvt8(v);
    } else {
      bf16x8 z = {0, 0, 0, 0, 0, 0, 0, 0};
      Bs[s] = z;
    }
  }

  for (int tt = 0; tt < 8; ++tt) {
    const int tile = wtile * 8 + tt;
    if (tile >= (EE / 16)) break;
    const int e0 = tile * 16;

    const float* arow = rfeat + ((size_t)r * EE + e0 + c) * DD + kr * 8;
    const bf16x8 A0 = cvt8(arow);
    const bf16x8 A1 = cvt8(arow + 32);

    f32x4 z4 = {0.f, 0.f, 0.f, 0.f};
    f32x4 Cu[4], Cm[4], Cs;
#pragma unroll
    for (int t = 0; t < 4; ++t) { Cu[t] = z4; Cm[t] = z4; }
    Cs = z4;

#pragma unroll
    for (int t = 0; t < 4; ++t) {
      Cu[t] = __builtin_amdgcn_mfma_f32_16x16x32_bf16(A0, Bu[t][0], Cu[t], 0, 0, 0);
      Cu[t] = __builtin_amdgcn_mfma_f32_16x16x32_bf16(A1, Bu[t][1], Cu[t], 0, 0, 0);
      Cm[t] = __builtin_amdgcn_mfma_f32_16x16x32_bf16(A0, Bm[t][0], Cm[t], 0, 0, 0);
      Cm[t] = __builtin_amdgcn_mfma_f32_16x16x32_bf16(A1, Bm[t][1], Cm[t], 0, 0, 0);
    }
    Cs = __builtin_amdgcn_mfma_f32_16x16x32_bf16(A0, Bs[0], Cs, 0, 0, 0);
    Cs = __builtin_amdgcn_mfma_f32_16x16x32_bf16(A1, Bs[1], Cs, 0, 0, 0);

    const int ebase = r * EE + e0;
#pragma unroll
    for (int q = 0; q < 4; ++q) {
      const int rr = kr * 4 + q;
      const int e  = ebase + rr;
      const int src = (lane & 48);
      const float su = __shfl(Cs[q], src);
      const float pu = __shfl(Cs[q], src | 1);
      const float sm = __shfl(Cs[q], src | 2);
      const float pm = __shfl(Cs[q], src | 3);
      const float sgu = sigm(su), pau = sigm(pu);
      const float sgm_ = sigm(sm), pam = sigm(pm);

      const int eu = edges_u[e];
      const int em = edges_m[e];
      const float cju = user_cj[eu];
      const float cjm = movie_cj[em];

      const float4 hu = *(const float4*)(W_user + ((size_t)r * NU + eu) * DD + 4 * c);
      const float4 hm = *(const float4*)(W_movie + ((size_t)r * NM + em) * DD + 4 * c);

      const int slm = slot_m[e];
      const int slu = slot_u[e];

      short4 vm, vu;
      vm.x = f2bf((hu.x * pau + Cu[0][q] * sgu) * cju);
      vm.y = f2bf((hu.y * pau + Cu[1][q] * sgu) * cju);
      vm.z = f2bf((hu.z * pau + Cu[2][q] * sgu) * cju);
      vm.w = f2bf((hu.w * pau + Cu[3][q] * sgu) * cju);
      vu.x = f2bf((hm.x * pam + Cm[0][q] * sgm_) * cjm);
      vu.y = f2bf((hm.y * pam + Cm[1][q] * sgm_) * cjm);
      vu.z = f2bf((hm.z * pam + Cm[2][q] * sgm_) * cjm);
      vu.w = f2bf((hm.w * pam + Cm[3][q] * sgm_) * cjm);

      *(short4*)(msg_m + ((size_t)slm << 6) + 4 * c) = vm;
      *(short4*)(msg_u + ((size_t)slu << 6) + 4 * c) = vu;
    }
  }
}

// ---------------------------------------------------------------------------
// Gather-reduce: one wave per destination node; sum its contiguous segment.
// Writes d_out directly (covers every row -> no memset needed).
// ---------------------------------------------------------------------------
__global__ __launch_bounds__(256) void gather_k(const int* __restrict__ off,
                                                const short* __restrict__ msg_m,
                                                const short* __restrict__ msg_u,
                                                float* __restrict__ out)
{
  const int w    = blockIdx.x * 4 + (threadIdx.x >> 6);
  const int lane = threadIdx.x & 63;
  const int grp  = lane >> 4;
  const int cc   = lane & 15;

  const bool isM = (w < NM);
  const int s0 = off[w]     - (isM ? 0 : NE);
  const int e0 = off[w + 1] - (isM ? 0 : NE);
  const short* msg = isM ? msg_m : msg_u;
  float* dst = isM ? (out + (size_t)NU * DD + (size_t)w * DD)
                   : (out + (size_t)(w - NM) * DD);

  float4 acc = {0.f, 0.f, 0.f, 0.f};
  for (int k = s0 + grp; k < e0; k += 4) {
    const short4 v = *(const short4*)(msg + ((size_t)k << 6) + 4 * cc);
    acc.x += bf2f(v.x); acc.y += bf2f(v.y);
    acc.z += bf2f(v.z); acc.w += bf2f(v.w);
  }
  acc.x += __shfl_xor(acc.x, 16); acc.y += __shfl_xor(acc.y, 16);
  acc.z += __shfl_xor(acc.z, 16); acc.w += __shfl_xor(acc.w, 16);
  acc.x += __shfl_xor(acc.x, 32); acc.y += __shfl_xor(acc.y, 32);
  acc.z += __shfl_xor(acc.z, 32); acc.w += __shfl_xor(acc.w, 32);
  if (grp == 0) *(float4*)(dst + 4 * cc) = acc;
}

// ---------------------------------------------------------------------------
// Fallback (atomic) main kernel — used only if ws_size is too small.
// ---------------------------------------------------------------------------
__global__ __launch_bounds__(256) void gcmc_main_atomic(
    const int* __restrict__ edges_u, const int* __restrict__ edges_m,
    const float* __restrict__ rfeat,
    const float* __restrict__ W_user, const float* __restrict__ W_movie,
    const float* __restrict__ ps_u, const float* __restrict__ rs_u, const float* __restrict__ rw_u,
    const float* __restrict__ ps_m, const float* __restrict__ rs_m, const float* __restrict__ rw_m,
    const float* __restrict__ user_cj, const float* __restrict__ movie_cj,
    float* __restrict__ user_agg, float* __restrict__ movie_agg)
{
  const int r    = blockIdx.y;
  const int lane = threadIdx.x & 63;
  const int wid  = threadIdx.x >> 6;
  const int c    = lane & 15;
  const int kr   = lane >> 4;
  const int wtile = blockIdx.x * 4 + wid;

  bf16x8 Bu[4][2], Bm[4][2], Bs[2];
#pragma unroll
  for (int t = 0; t < 4; ++t)
#pragma unroll
    for (int s = 0; s < 2; ++s) {
      Bu[t][s] = cvt8(rw_u + ((size_t)r * DD + (4 * c + t)) * DD + s * 32 + kr * 8);
      Bm[t][s] = cvt8(rw_m + ((size_t)r * DD + (4 * c + t)) * DD + s * 32 + kr * 8);
    }
#pragma unroll
  for (int s = 0; s < 2; ++s) {
    if (c < 4) {
      const float* v = (c == 0 ? rs_u : c == 1 ? ps_u : c == 2 ? rs_m : ps_m)
                       + r * DD + s * 32 + kr * 8;
      Bs[s] = cvt8(v);
    } else { bf16x8 z = {0,0,0,0,0,0,0,0}; Bs[s] = z; }
  }

  for (int tt = 0; tt < 8; ++tt) {
    const int tile = wtile * 8 + tt;
    if (tile >= (EE / 16)) break;
    const int e0 = tile * 16;
    const float* arow = rfeat + ((size_t)r * EE + e0 + c) * DD + kr * 8;
    const bf16x8 A0 = cvt8(arow);
    const bf16x8 A1 = cvt8(arow + 32);
    f32x4 z4 = {0.f,0.f,0.f,0.f};
    f32x4 Cu[4], Cm[4], Cs;
#pragma unroll
    for (int t = 0; t < 4; ++t) { Cu[t] = z4; Cm[t] = z4; }
    Cs = z4;
#pragma unroll
    for (int t = 0; t < 4; ++t) {
      Cu[t] = __builtin_amdgcn_mfma_f32_16x16x32_bf16(A0, Bu[t][0], Cu[t], 0, 0, 0);
      Cu[t] = __builtin_amdgcn_mfma_f32_16x16x32_bf16(A1, Bu[t][1], Cu[t], 0, 0, 0);
      Cm[t] = __builtin_amdgcn_mfma_f32_16x16x32_bf16(A0, Bm[t][0], Cm[t], 0, 0, 0);
      Cm[t] = __builtin_amdgcn_mfma_f32_16x16x32_bf16(A1, Bm[t][1], Cm[t], 0, 0, 0);
    }
    Cs = __builtin_amdgcn_mfma_f32_16x16x32_bf16(A0, Bs[0], Cs, 0, 0, 0);
    Cs = __builtin_amdgcn_mfma_f32_16x16x32_bf16(A1, Bs[1], Cs, 0, 0, 0);

    const int ebase = r * EE + e0;
#pragma unroll
    for (int q = 0; q < 4; ++q) {
      const int e  = ebase + kr * 4 + q;
      const int src = (lane & 48);
      const float su = __shfl(Cs[q], src);
      const float pu = __shfl(Cs[q], src | 1);
      const float sm = __shfl(Cs[q], src | 2);
      const float pm = __shfl(Cs[q], src | 3);
      const float sgu = sigm(su), pau = sigm(pu);
      const float sgm_ = sigm(sm), pam = sigm(pm);
      const int eu = edges_u[e];
      const int em = edges_m[e];
      const float cju = user_cj[eu];
      const float cjm = movie_cj[em];
      const float4 hu = *(const float4*)(W_user + ((size_t)r * NU + eu) * DD + 4 * c);
      const float4 hm = *(const float4*)(W_movie + ((size_t)r * NM + em) * DD + 4 * c);
      float* mdst = movie_agg + (size_t)em * DD + 4 * c;
      float* udst = user_agg + (size_t)eu * DD + 4 * c;
      atomicAdd(mdst + 0, (hu.x * pau + Cu[0][q] * sgu) * cju);
      atomicAdd(mdst + 1, (hu.y * pau + Cu[1][q] * sgu) * cju);
      atomicAdd(mdst + 2, (hu.z * pau + Cu[2][q] * sgu) * cju);
      atomicAdd(mdst + 3, (hu.w * pau + Cu[3][q] * sgu) * cju);
      atomicAdd(udst + 0, (hm.x * pam + Cm[0][q] * sgm_) * cjm);
      atomicAdd(udst + 1, (hm.y * pam + Cm[1][q] * sgm_) * cjm);
      atomicAdd(udst + 2, (hm.z * pam + Cm[2][q] * sgm_) * cjm);
      atomicAdd(udst + 3, (hm.w * pam + Cm[3][q] * sgm_) * cjm);
    }
  }
}

// ---------------------------------------------------------------------------
// FC kernel (in-place on d_out): row -> gelu(row*ci) @ W.T + b, 16 rows/wave.
// ---------------------------------------------------------------------------
__global__ __launch_bounds__(256) void gcmc_fc(
    float* __restrict__ out,
    const float* __restrict__ user_ci, const float* __restrict__ movie_ci,
    const float* __restrict__ ufc_w, const float* __restrict__ ufc_b,
    const float* __restrict__ ifc_w, const float* __restrict__ ifc_b)
{
  const int wt   = blockIdx.x * 4 + (threadIdx.x >> 6);
  const int lane = threadIdx.x & 63;
  const int c    = lane & 15;
  const int kr   = lane >> 4;
  const bool isU = wt < (NU / 16);
  float* base        = isU ? out : out + (size_t)NU * DD;
  const float* ci    = isU ? user_ci : movie_ci;
  const float* W     = isU ? ufc_w : ifc_w;
  const float* bias  = isU ? ufc_b : ifc_b;
  const int row0 = (isU ? wt : wt - (NU / 16)) * 16;

  bf16x8 B[4][2];
#pragma unroll
  for (int t = 0; t < 4; ++t)
#pragma unroll
    for (int s = 0; s < 2; ++s)
      B[t][s] = cvt8(W + (size_t)(4 * c + t) * DD + s * 32 + kr * 8);

  const float civ = ci[row0 + c];
  const float* arow = base + (size_t)(row0 + c) * DD + kr * 8;

  bf16x8 A0, A1;
  {
    const float4 a = *(const float4*)arow;
    const float4 b = *(const float4*)(arow + 4);
    const float4 a2 = *(const float4*)(arow + 32);
    const float4 b2 = *(const float4*)(arow + 36);
    A0[0] = f2bf(gelu(a.x * civ));  A0[1] = f2bf(gelu(a.y * civ));
    A0[2] = f2bf(gelu(a.z * civ));  A0[3] = f2bf(gelu(a.w * civ));
    A0[4] = f2bf(gelu(b.x * civ));  A0[5] = f2bf(gelu(b.y * civ));
    A0[6] = f2bf(gelu(b.z * civ));  A0[7] = f2bf(gelu(b.w * civ));
    A1[0] = f2bf(gelu(a2.x * civ)); A1[1] = f2bf(gelu(a2.y * civ));
    A1[2] = f2bf(gelu(a2.z * civ)); A1[3] = f2bf(gelu(a2.w * civ));
    A1[4] = f2bf(gelu(b2.x * civ)); A1[5] = f2bf(gelu(b2.y * civ));
    A1[6] = f2bf(gelu(b2.z * civ)); A1[7] = f2bf(gelu(b2.w * civ));
  }

  f32x4 z4 = {0.f, 0.f, 0.f, 0.f};
  f32x4 C[4];
#pragma unroll
  for (int t = 0; t < 4; ++t) {
    C[t] = z4;
    C[t] = __builtin_amdgcn_mfma_f32_16x16x32_bf16(A0, B[t][0], C[t], 0, 0, 0);
    C[t] = __builtin_amdgcn_mfma_f32_16x16x32_bf16(A1, B[t][1], C[t], 0, 0, 0);
  }

  const float4 b4 = *(const float4*)(bias + 4 * c);
#pragma unroll
  for (int q = 0; q < 4; ++q) {
    const int row = row0 + kr * 4 + q;
    float4 o;
    o.x = C[0][q] + b4.x; o.y = C[1][q] + b4.y;
    o.z = C[2][q] + b4.z; o.w = C[3][q] + b4.w;
    *(float4*)(base + (size_t)row * DD + 4 * c) = o;
  }
}

extern "C" void kernel_launch(void* const* d_in, const int* in_sizes, int n_in,
                              void* d_out, int out_size, void* d_ws, size_t ws_size,
                              hipStream_t stream) {
  const int*   edges_u  = (const int*)  d_in[0];
  const int*   edges_m  = (const int*)  d_in[1];
  const float* rfeat    = (const float*)d_in[2];
  const float* W_user   = (const float*)d_in[3];
  const float* W_movie  = (const float*)d_in[4];
  const float* ps_u     = (const float*)d_in[5];
  const float* rs_u     = (const float*)d_in[6];
  const float* rw_u     = (const float*)d_in[7];
  const float* ps_m     = (const float*)d_in[8];
  const float* rs_m     = (const float*)d_in[9];
  const float* rw_m     = (const float*)d_in[10];
  const float* user_cj  = (const float*)d_in[11];
  const float* user_ci  = (const float*)d_in[12];
  const float* movie_cj = (const float*)d_in[13];
  const float* movie_ci = (const float*)d_in[14];
  const float* ufc_w    = (const float*)d_in[15];
  const float* ufc_b    = (const float*)d_in[16];
  const float* ifc_w    = (const float*)d_in[17];
  const float* ifc_b    = (const float*)d_in[18];

  float* out = (float*)d_out;
  float* user_agg  = out;
  float* movie_agg = out + (size_t)NU * DD;

  // ---- workspace layout ----
  char* ws = (char*)d_ws;
  size_t o = 0;
  auto alloc = [&](size_t bytes) { char* p = ws + o; o += (bytes + 255) & ~(size_t)255; return p; };
  int*   cnt    = (int*)  alloc(sizeof(int) * NNODE);
  int*   off    = (int*)  alloc(sizeof(int) * (NNODE + 1));
  int*   cur    = (int*)  alloc(sizeof(int) * NNODE);
  int*   slot_m = (int*)  alloc(sizeof(int) * NE);
  int*   slot_u = (int*)  alloc(sizeof(int) * NE);
  short* msg_m  = (short*)alloc(sizeof(short) * (size_t)NE * DD);
  short* msg_u  = (short*)alloc(sizeof(short) * (size_t)NE * DD);
  const bool sorted_ok = (o <= ws_size);

  dim3 g1((EE / 16 + 31) / 32, RR);

  if (sorted_ok) {
    hipMemsetAsync(cnt, 0, sizeof(int) * NNODE, stream);
    hist_k<<<(NE + 255) / 256, 256, 0, stream>>>(edges_u, edges_m, cnt);
    scan_k<<<1, 1024, 0, stream>>>(cnt, off);
    hipMemcpyAsync(cur, off, sizeof(int) * NNODE, hipMemcpyDeviceToDevice, stream);
    rank_k<<<(NE + 255) / 256, 256, 0, stream>>>(edges_u, edges_m, cur, slot_m, slot_u);

    gcmc_main_sorted<<<g1, 256, 0, stream>>>(edges_u, edges_m, rfeat, W_user, W_movie,
                                             ps_u, rs_u, rw_u, ps_m, rs_m, rw_m,
                                             user_cj, movie_cj, slot_m, slot_u,
                                             msg_m, msg_u);

    gather_k<<<NNODE / 4, 256, 0, stream>>>(off, msg_m, msg_u, out);
  } else {
    hipMemsetAsync(out, 0, (size_t)out_size * sizeof(float), stream);
    gcmc_main_atomic<<<g1, 256, 0, stream>>>(edges_u, edges_m, rfeat, W_user, W_movie,
                                             ps_u, rs_u, rw_u, ps_m, rs_m, rw_m,
                                             user_cj, movie_cj, user_agg, movie_agg);
  }

  gcmc_fc<<<(NNODE / 16) / 4, 256, 0, stream>>>(out, user_ci, movie_ci,
                                                ufc_w, ufc_b, ifc_w, ifc_b);
}